// Round 10
// baseline (214.833 us; speedup 1.0000x reference)
//
#include <hip/hip_runtime.h>

typedef _Float16 f16;
typedef _Float16 f16x8 __attribute__((ext_vector_type(8)));
typedef float f32x4 __attribute__((ext_vector_type(4)));

#define INV_R (1.0f / 40.0f)

// ---- workspace layout (bytes), ~9.6 MB ----
#define W_HTA 0u             // f16 [80][512]
#define W_HTB 81920u         // f16 [80][512]
#define W_KT0 163840u        // f16 [64][4320]  layer-0 fused kernel (conv|dense|pad)
#define W_TA  716800u        // f16 [512][4320] layer-0 t  (alias: 4160-wide for L2/L4)
#define W_TB  5140480u       // f16 [512][4160] t for L1/L3
#define W_OG  9400320u       // f32 [512][64]   residual

// ================= math helpers =================
__device__ __forceinline__ float feats0_val(int ch, int n, const float* v, const float* other) {
  if (ch == 0) return 1.0f;
  if (ch < 4) return v[n * 3 + (ch - 1)];
  return other[n * 62 + (ch - 4)];
}
__device__ __forceinline__ float atan_poly(float t) {
  float t2 = t * t;
  float p = -0.0117212f;
  p = p * t2 + 0.05265332f;
  p = p * t2 - 0.11643287f;
  p = p * t2 + 0.19354346f;
  p = p * t2 - 0.33262347f;
  p = p * t2 + 0.99997726f;
  return t * p;
}
__device__ __forceinline__ void axis_w(float g, int& i0c, int& i1c, float& w0, float& w1) {
  float c = 2.0f * g + 1.5f;
  float fl = floorf(c);
  float f = c - fl;
  int i0 = (int)fl;
  w0 = (i0 >= 0 && i0 <= 3) ? (1.0f - f) : 0.0f;
  w1 = (i0 >= -1 && i0 <= 2) ? f : 0.0f;
  i0c = min(max(i0, 0), 3);
  i1c = min(max(i0 + 1, 0), 3);
}

// ============ prep: hT0 (feats0^T) + packed f16 KT0 only ============
__global__ __launch_bounds__(256) void prep_k(const float* __restrict__ v,
                                              const float* __restrict__ other,
                                              const float* __restrict__ kf,
                                              const float* __restrict__ Wf,
                                              f16* __restrict__ hT0, f16* __restrict__ KT0) {
  for (int e = blockIdx.x * 256 + threadIdx.x; e < 317440; e += 512 * 256) {
    if (e < 40960) {                       // hT0: rows 66..79 zero
      int i = e >> 9, n = e & 511;
      hT0[e] = (f16)((i < 66) ? feats0_val(i, n, v, other) : 0.0f);
    } else {                               // KT0: rows 0..31 conv | rows 32..63 dense tail
      int ee = e - 40960;
      int o = ee / 4320, k = ee % 4320;
      float val = 0.0f;
      if (o < 32) { if (k < 4224) val = kf[o * 4224 + k]; }
      else if (k >= 4224 && k < 4290) val = Wf[(o - 32) * 66 + (k - 4224)];
      KT0[ee] = (f16)val;
    }
  }
}

// ============ stage 1: per m (=blockIdx.x), W-scatter in LDS + MFMA -> t row ============
template<int CI, int ITILES, int KDIM, bool TAIL0>
__global__ __launch_bounds__(256) void stage1_k(const float* __restrict__ p,
                                                const float* __restrict__ mask,
                                                const float* __restrict__ v,
                                                const float* __restrict__ other,
                                                const f16* __restrict__ hT_in,
                                                f16* __restrict__ tout) {
  __shared__ f16 Wl[64 * 256];             // 32 KB, XOR-swizzled rows
  const int tid = threadIdx.x;
  const int m = blockIdx.x;
  const int wave = tid >> 6, lane = tid & 63;
  const int row = lane & 15, kgrp = lane >> 4;
  const int grow = wave * 16 + row;

  const float pmx = p[m * 3 + 0], pmy = p[m * 3 + 1], pmz = p[m * 3 + 2];
  f32x4 acc[ITILES];
  #pragma unroll
  for (int it = 0; it < ITILES; ++it) acc[it] = f32x4{0.f, 0.f, 0.f, 0.f};

  #pragma unroll
  for (int half = 0; half < 2; ++half) {
    __syncthreads();
    int4* w4 = (int4*)Wl;
    int4 z4 = make_int4(0, 0, 0, 0);
    #pragma unroll
    for (int i = 0; i < 8; ++i) w4[tid + i * 256] = z4;
    __syncthreads();
    {
      const int n = half * 256 + tid;
      float x = (p[n * 3 + 0] - pmx) * INV_R;
      float y = (p[n * 3 + 1] - pmy) * INV_R;
      float z = (p[n * 3 + 2] - pmz) * INV_R;
      float r2 = x * x + y * y + z * z;
      float q = 1.0f - r2;
      float att = (q > 0.0f) ? q * q * q * mask[n] : 0.0f;
      bool c1 = (x == 0.0f) && (y == 0.0f);
      bool c2 = (fabsf(y) <= fabsf(x)) && !c1;
      float r = sqrtf(x * x + y * y + 1e-9f);
      float num = c2 ? y : x;
      float den = c2 ? x : y;
      float a = atan_poly(num / den);
      float s2 = copysignf(r, x), s3 = copysignf(r, y);
      const float C4PI = 1.2732395447351628f;
      float xs = c1 ? 0.0f : (c2 ? s2 : C4PI * s3 * a);
      float ys = c1 ? 0.0f : (c2 ? C4PI * s2 * a : s3);
      float zs = z;
      int iz0, iz1, iy0, iy1, ix0, ix1;
      float wz0, wz1, wy0, wy1, wx0, wx1;
      axis_w(zs, iz0, iz1, wz0, wz1);
      axis_w(ys, iy0, iy1, wy0, wy1);
      axis_w(xs, ix0, ix1, wx0, wx1);
      wz0 *= att; wz1 *= att;
      int gz[2] = {iz0 * 16, iz1 * 16};
      int gy[2] = {iy0 * 4, iy1 * 4};
      int gx[2] = {ix0, ix1};
      float wzv[2] = {wz0, wz1}, wyv[2] = {wy0, wy1}, wxv[2] = {wx0, wx1};
      #pragma unroll
      for (int za = 0; za < 2; ++za)
        #pragma unroll
        for (int ya = 0; ya < 2; ++ya)
          #pragma unroll
          for (int xa = 0; xa < 2; ++xa) {
            float w = wzv[za] * wyv[ya] * wxv[xa];
            if (w != 0.0f) {
              int g = gz[za] + gy[ya] + gx[xa];
              Wl[g * 256 + (tid ^ ((g & 7) << 3))] = (f16)w;
            }
          }
    }
    __syncthreads();
    #pragma unroll
    for (int k0 = 0; k0 < 8; ++k0) {
      const int n0l = k0 * 32 + kgrp * 8;
      f16x8 afrag = *(f16x8*)&Wl[grow * 256 + (n0l ^ ((grow & 7) << 3))];
      f16x8 bfr[ITILES];
      #pragma unroll
      for (int it = 0; it < ITILES; ++it)
        bfr[it] = *(const f16x8*)&hT_in[(it * 16 + row) * 512 + half * 256 + n0l];
      #pragma unroll
      for (int it = 0; it < ITILES; ++it)
        acc[it] = __builtin_amdgcn_mfma_f32_16x16x32_f16(afrag, bfr[it], acc[it], 0, 0, 0);
    }
  }
  const int g4 = wave * 16 + kgrp * 4;
  #pragma unroll
  for (int it = 0; it < ITILES; ++it) {
    const int icol = it * 16 + row;
    if (icol < CI) {
      union { f16 h[4]; short4 s; } cv;
      #pragma unroll
      for (int r = 0; r < 4; ++r) cv.h[r] = (f16)acc[it][r];
      *(short4*)&tout[(size_t)m * KDIM + icol * 64 + g4] = cv.s;   // [m][i*64+g]
    }
  }
  if (TAIL0) {                              // layer-0 dense tail (96-wide pad)
    if (tid < 96)
      tout[(size_t)m * KDIM + 4224 + tid] =
          (f16)((tid < 66) ? feats0_val(tid, m, v, other) : 0.0f);
  }
}

// ============ stage 2, layer 0: t(4320) x KT0 f16 (prep-packed) ============
__global__ __launch_bounds__(256) void stage2f16_k(const f16* __restrict__ t,
                                                   const f16* __restrict__ Kf,
                                                   const float* __restrict__ bf,
                                                   float* __restrict__ outG,
                                                   f16* __restrict__ hT_out,
                                                   f16* __restrict__ tnext) {
  __shared__ float red[3 * 256];
  constexpr int KSTEPS = 135;               // 4320/32
  int b = blockIdx.x;
  int mtile = b >> 2, otile = b & 3;
  int tid = threadIdx.x;
  int kpart = tid >> 6, lane = tid & 63;
  int row = lane & 15, kgrp = lane >> 4;
  int mrow = mtile * 16 + row;
  int ocol = otile * 16 + row;
  f32x4 acc = {0.f, 0.f, 0.f, 0.f};
  for (int ks = kpart; ks < KSTEPS; ks += 4) {
    int k0 = ks * 32 + kgrp * 8;
    f16x8 afrag = *(const f16x8*)&t[(size_t)mrow * 4320 + k0];
    f16x8 bfrag = *(const f16x8*)&Kf[(size_t)ocol * 4320 + k0];
    acc = __builtin_amdgcn_mfma_f32_16x16x32_f16(afrag, bfrag, acc, 0, 0, 0);
  }
  if (kpart > 0) {
    #pragma unroll
    for (int r = 0; r < 4; ++r)
      red[(kpart - 1) * 256 + (kgrp * 4 + r) * 16 + row] = acc[r];
  }
  __syncthreads();
  if (kpart == 0) {
    #pragma unroll
    for (int kw = 0; kw < 3; ++kw)
      #pragma unroll
      for (int r = 0; r < 4; ++r)
        acc[r] += red[kw * 256 + (kgrp * 4 + r) * 16 + row];
    #pragma unroll
    for (int r = 0; r < 4; ++r) {
      int mm = mtile * 16 + kgrp * 4 + r;
      int oo = otile * 16 + row;
      float bb = (oo < 32) ? 0.0f : bf[oo - 32];
      float val = acc[r] + bb;
      outG[mm * 64 + oo] = val;
      float h = fmaxf(val, 0.0f);
      hT_out[oo * 512 + mm] = (f16)h;
      tnext[(size_t)mm * 4160 + 4096 + oo] = (f16)h;
    }
  }
}

// ============ stage 2, layers 1-4: t(4160) x raw fp32 kernel (inline cvt) ============
template<bool RES, bool FINAL>
__global__ __launch_bounds__(256) void stage2f32_k(const f16* __restrict__ t,
                                                   const float* __restrict__ kk,
                                                   const float* __restrict__ WW,
                                                   const float* __restrict__ bias,
                                                   float* __restrict__ outG,
                                                   f16* __restrict__ hT_out,
                                                   f16* __restrict__ tnext,
                                                   float* __restrict__ dout) {
  __shared__ float red[3 * 256];
  constexpr int KSTEPS = 130;               // 4160/32
  constexpr int OMAX = FINAL ? 6 : 64;
  int b = blockIdx.x;
  int mtile = b >> 2, otile = b & 3;
  int tid = threadIdx.x;
  int kpart = tid >> 6, lane = tid & 63;
  int row = lane & 15, kgrp = lane >> 4;
  int mrow = mtile * 16 + row;
  int ocol = otile * 16 + row;
  bool ovalid = (ocol < OMAX);
  f32x4 acc = {0.f, 0.f, 0.f, 0.f};
  for (int ks = kpart; ks < KSTEPS; ks += 4) {
    int k0 = ks * 32 + kgrp * 8;
    f16x8 afrag = *(const f16x8*)&t[(size_t)mrow * 4160 + k0];
    union { f16 h[8]; f16x8 v8; } ub;
    if (k0 < 4096) {                        // conv region (k0 <= 4088)
      if (ovalid) {
        const float* cp = kk + (size_t)ocol * 4096 + k0;
        float4 x = *(const float4*)cp;
        float4 y = *(const float4*)(cp + 4);
        ub.h[0] = (f16)x.x; ub.h[1] = (f16)x.y; ub.h[2] = (f16)x.z; ub.h[3] = (f16)x.w;
        ub.h[4] = (f16)y.x; ub.h[5] = (f16)y.y; ub.h[6] = (f16)y.z; ub.h[7] = (f16)y.w;
      } else {
        #pragma unroll
        for (int e = 0; e < 8; ++e) ub.h[e] = (f16)0.0f;
      }
    } else {                                // dense tail, j in 0..56
      int j = k0 - 4096;
      #pragma unroll
      for (int e = 0; e < 8; ++e)
        ub.h[e] = (f16)(ovalid ? WW[ocol * 64 + j + e] : 0.0f);
    }
    acc = __builtin_amdgcn_mfma_f32_16x16x32_f16(afrag, ub.v8, acc, 0, 0, 0);
  }
  if (kpart > 0) {
    #pragma unroll
    for (int r = 0; r < 4; ++r)
      red[(kpart - 1) * 256 + (kgrp * 4 + r) * 16 + row] = acc[r];
  }
  __syncthreads();
  if (kpart == 0) {
    #pragma unroll
    for (int kw = 0; kw < 3; ++kw)
      #pragma unroll
      for (int r = 0; r < 4; ++r)
        acc[r] += red[kw * 256 + (kgrp * 4 + r) * 16 + row];
    #pragma unroll
    for (int r = 0; r < 4; ++r) {
      int mm = mtile * 16 + kgrp * 4 + r;
      int oo = otile * 16 + row;
      if (FINAL) {
        if (oo < 6) dout[mm * 6 + oo] = acc[r] + bias[oo];
      } else {
        float val = acc[r] + bias[oo];
        if (RES) val += outG[mm * 64 + oo];
        outG[mm * 64 + oo] = val;
        float h = fmaxf(val, 0.0f);
        hT_out[oo * 512 + mm] = (f16)h;
        tnext[(size_t)mm * 4160 + 4096 + oo] = (f16)h;
      }
    }
  }
}

extern "C" void kernel_launch(void* const* d_in, const int* in_sizes, int n_in,
                              void* d_out, int out_size, void* d_ws, size_t ws_size,
                              hipStream_t stream) {
  const float* p     = (const float*)d_in[0];
  const float* v     = (const float*)d_in[1];
  const float* other = (const float*)d_in[2];
  const float* mask  = (const float*)d_in[3];
  const float* kf    = (const float*)d_in[4];
  const float* Wf    = (const float*)d_in[5];
  const float* bf    = (const float*)d_in[6];
  const float* k1    = (const float*)d_in[7];
  const float* W1    = (const float*)d_in[8];
  const float* b1    = (const float*)d_in[9];
  const float* k2    = (const float*)d_in[10];
  const float* W2    = (const float*)d_in[11];
  const float* b2    = (const float*)d_in[12];
  const float* k3    = (const float*)d_in[13];
  const float* W3    = (const float*)d_in[14];
  const float* b3    = (const float*)d_in[15];
  const float* k4    = (const float*)d_in[16];
  const float* W4    = (const float*)d_in[17];
  const float* b4    = (const float*)d_in[18];
  float* dout = (float*)d_out;
  char* ws = (char*)d_ws;
  (void)in_sizes; (void)n_in; (void)out_size; (void)ws_size;

  f16* hTA = (f16*)(ws + W_HTA);
  f16* hTB = (f16*)(ws + W_HTB);
  f16* KT0 = (f16*)(ws + W_KT0);
  f16* tA  = (f16*)(ws + W_TA);    // 4320-wide for layer 0
  f16* tC  = (f16*)(ws + W_TA);    // same memory, 4160-wide for layers 2/4
  f16* tB  = (f16*)(ws + W_TB);    // 4160-wide for layers 1/3
  float* outG = (float*)(ws + W_OG);

  prep_k<<<512, 256, 0, stream>>>(v, other, kf, Wf, hTA, KT0);

  // layer 0
  stage1_k<66, 5, 4320, true><<<512, 256, 0, stream>>>(p, mask, v, other, hTA, tA);
  stage2f16_k<<<128, 256, 0, stream>>>(tA, KT0, bf, outG, hTB, tB);
  // layer 1
  stage1_k<64, 4, 4160, false><<<512, 256, 0, stream>>>(p, mask, v, other, hTB, tB);
  stage2f32_k<true, false><<<128, 256, 0, stream>>>(tB, k1, W1, b1, outG, hTA, tC, nullptr);
  // layer 2
  stage1_k<64, 4, 4160, false><<<512, 256, 0, stream>>>(p, mask, v, other, hTA, tC);
  stage2f32_k<true, false><<<128, 256, 0, stream>>>(tC, k2, W2, b2, outG, hTB, tB, nullptr);
  // layer 3
  stage1_k<64, 4, 4160, false><<<512, 256, 0, stream>>>(p, mask, v, other, hTB, tB);
  stage2f32_k<true, false><<<128, 256, 0, stream>>>(tB, k3, W3, b3, outG, hTA, tC, nullptr);
  // layer 4 -> d_out
  stage1_k<64, 4, 4160, false><<<512, 256, 0, stream>>>(p, mask, v, other, hTA, tC);
  stage2f32_k<false, true><<<128, 256, 0, stream>>>(tC, k4, W4, b4, nullptr, nullptr, nullptr, dout);
}

// Round 11
// 190.160 us; speedup vs baseline: 1.1297x; 1.1297x over previous
//
#include <hip/hip_runtime.h>

typedef _Float16 f16;
typedef _Float16 f16x8 __attribute__((ext_vector_type(8)));
typedef float f32x4 __attribute__((ext_vector_type(4)));
typedef int iv2 __attribute__((ext_vector_type(2)));

#define INV_R (1.0f / 40.0f)
#define NBLK 512

// ---- FULL layout (cooperative path), bytes ----
#define F_BAR 0u             // u32[576]
#define F_B0  2304u          // f32[64] layer-0 fused bias (zeros ++ bf)
#define F_K   2560u          // K0|K1|K2|K3|K4 contiguous (f16)
#define F_HT  2286080u       // 5 x f16[80][512]
#define F_T0  2695680u       // f16[512][4320]
#define F_T1  7119360u       // f16[512][4160]
#define F_T2  11379200u
#define F_T3  15639040u
#define F_T4  19898880u
#define F_OG  24158720u      // f32[512][64] residual (block-private)
#define NEED_FULL 24289792u

// ---- COMPACT layout (fallback path), bytes ----
#define C_B0  2304u
#define C_K   2560u
#define C_HTA 2286080u
#define C_HTB 2368000u
#define C_TA  2449920u       // 4320-wide buffer
#define C_TB  6873600u       // 4160-wide buffer
#define C_OG  11133440u

// K sub-offsets in bytes from K base: K0 [64][4320], K1..K3 [64][4160], K4 [16][4160]
#define K1_OFF 552960u
#define K2_OFF 1085440u
#define K3_OFF 1617920u
#define K4_OFF 2150400u

#define PREP_TOTAL 1231936

// ---- system-scope stores (write-through to coherent point) ----
__device__ __forceinline__ void st_sys_u16(void* p, unsigned v) {
  asm volatile("global_store_short %0, %1, off sc0 sc1" :: "v"(p), "v"(v) : "memory");
}
__device__ __forceinline__ void st_sys_f32(float* p, float v) {
  asm volatile("global_store_dword %0, %1, off sc0 sc1" :: "v"(p), "v"(v) : "memory");
}
__device__ __forceinline__ void st_sys_b64(void* p, iv2 v) {
  asm volatile("global_store_dwordx2 %0, %1, off sc0 sc1" :: "v"(p), "v"(v) : "memory");
}
__device__ __forceinline__ unsigned f16bits(float x) {
  union { f16 h; unsigned short s; } cv; cv.h = (f16)x; return (unsigned)cv.s;
}

// ============ fence-free hierarchical grid barrier ============
// r11 change: non-leader pollers back off with s_sleep(64) (~1.7us) so 384 idle
// blocks don't saturate the 8 xrel LLC lines with agent-scope loads (the
// hypothesized cause of stage2's ~35us: release-line slice saturation).
__device__ __forceinline__ unsigned bar_ld(unsigned* p) {
  return __hip_atomic_load(p, __ATOMIC_RELAXED, __HIP_MEMORY_SCOPE_AGENT);
}
__device__ void gridbar(unsigned* bar, int phase) {
  asm volatile("s_waitcnt vmcnt(0)" ::: "memory");   // drain sc01 stores
  __syncthreads();
  if (threadIdx.x == 0) {
    int bid = blockIdx.x;
    int xcd = bid & 7;
    unsigned* xcnt = bar + xcd * 32 + phase;
    unsigned* xrel = bar + 256 + xcd * 32 + phase;
    unsigned* gcnt = bar + 512 + phase;
    unsigned* grel = bar + 544 + phase;
    __hip_atomic_fetch_add(xcnt, 1u, __ATOMIC_RELAXED, __HIP_MEMORY_SCOPE_AGENT);
    if (bid < 8) {
      while (bar_ld(xcnt) < (NBLK / 8)) __builtin_amdgcn_s_sleep(2);   // 1 poller/line
      __hip_atomic_fetch_add(gcnt, 1u, __ATOMIC_RELAXED, __HIP_MEMORY_SCOPE_AGENT);
      if (bid == 0) {
        while (bar_ld(gcnt) < 8u) __builtin_amdgcn_s_sleep(2);         // 1 poller
        __hip_atomic_store(grel, 1u, __ATOMIC_RELAXED, __HIP_MEMORY_SCOPE_AGENT);
      } else {
        while (bar_ld(grel) == 0u) __builtin_amdgcn_s_sleep(4);        // 7 pollers
      }
      __hip_atomic_store(xrel, 1u, __ATOMIC_RELAXED, __HIP_MEMORY_SCOPE_AGENT);
    } else {
      while (bar_ld(xrel) == 0u) __builtin_amdgcn_s_sleep(64);         // 63/line, backoff
    }
    asm volatile("" ::: "memory");
  }
  __syncthreads();
}

// ================= math helpers =================
__device__ __forceinline__ float feats0_val(int ch, int n, const float* v, const float* other) {
  if (ch == 0) return 1.0f;
  if (ch < 4) return v[n * 3 + (ch - 1)];
  return other[n * 62 + (ch - 4)];
}
__device__ __forceinline__ float atan_poly(float t) {
  float t2 = t * t;
  float p = -0.0117212f;
  p = p * t2 + 0.05265332f;
  p = p * t2 - 0.11643287f;
  p = p * t2 + 0.19354346f;
  p = p * t2 - 0.33262347f;
  p = p * t2 + 0.99997726f;
  return t * p;
}
__device__ __forceinline__ void axis_w(float g, int& i0c, int& i1c, float& w0, float& w1) {
  float c = 2.0f * g + 1.5f;
  float fl = floorf(c);
  float f = c - fl;
  int i0 = (int)fl;
  w0 = (i0 >= 0 && i0 <= 3) ? (1.0f - f) : 0.0f;
  w1 = (i0 >= -1 && i0 <= 2) ? f : 0.0f;
  i0c = min(max(i0, 0), 3);
  i1c = min(max(i0 + 1, 0), 3);
}

// ============ prep: hT0, t0 dense tail, K0..K4 ([o][KDIM] rows), B0 — all sc01 ============
__device__ void prep_body(const float* __restrict__ v, const float* __restrict__ other,
                          const float* __restrict__ kf, const float* __restrict__ Wf,
                          const float* __restrict__ bf,
                          const float* __restrict__ k1, const float* __restrict__ W1,
                          const float* __restrict__ k2, const float* __restrict__ W2,
                          const float* __restrict__ k3, const float* __restrict__ W3,
                          const float* __restrict__ k4, const float* __restrict__ W4,
                          f16* __restrict__ K0, float* __restrict__ B0,
                          f16* __restrict__ hT0, f16* __restrict__ t0) {
  for (int idx = blockIdx.x * 256 + threadIdx.x; idx < PREP_TOTAL; idx += NBLK * 256) {
    int e = idx;
    if (e < 40960) {                         // hT0: feats0^T, rows 66..79 zero
      int i = e >> 9, n = e & 511;
      float val = (i < 66) ? feats0_val(i, n, v, other) : 0.0f;
      st_sys_u16(hT0 + e, f16bits(val));
      continue;
    }
    e -= 40960;
    if (e < 49152) {                         // t0 dense tail: feats0 per m, pad to 96
      int m = e / 96, j = e % 96;
      float val = (j < 66) ? feats0_val(j, m, v, other) : 0.0f;
      st_sys_u16(t0 + (size_t)m * 4320 + 4224 + j, f16bits(val));
      continue;
    }
    e -= 49152;
    if (e < 276480) {                        // K0: rows 0..31 conv, rows 32..63 dense tail
      int o = e / 4320, k = e % 4320;
      float val = 0.0f;
      if (o < 32) { if (k < 4224) val = kf[o * 4224 + k]; }
      else if (k >= 4224 && k < 4290) val = Wf[(o - 32) * 66 + (k - 4224)];
      st_sys_u16(K0 + e, f16bits(val));
      continue;
    }
    e -= 276480;
    if (e < 798720) {                        // K1..K3: conv 4096 | dense 64
      int which = e / 266240, ee = e % 266240;
      const float* kk = which == 0 ? k1 : (which == 1 ? k2 : k3);
      const float* WW = which == 0 ? W1 : (which == 1 ? W2 : W3);
      int o = ee / 4160, k = ee % 4160;
      float val = (k < 4096) ? kk[o * 4096 + k] : WW[o * 64 + (k - 4096)];
      st_sys_u16(K0 + (K1_OFF / 2) + (size_t)which * 266240 + ee, f16bits(val));
      continue;
    }
    e -= 798720;
    if (e < 66560) {                         // K4 (6 real rows, padded to 16)
      int o = e / 4160, k = e % 4160;
      float val = 0.0f;
      if (o < 6) val = (k < 4096) ? k4[o * 4096 + k] : W4[o * 64 + (k - 4096)];
      st_sys_u16(K0 + (K4_OFF / 2) + e, f16bits(val));
      continue;
    }
    e -= 66560;
    if (e < 64) st_sys_f32(&B0[e], (e < 32) ? 0.0f : bf[e - 32]);
  }
}

// ============ stage 1: per m (=blockIdx.x), W-scatter in LDS + MFMA -> t row (sc01) ============
template<int CI, int ITILES, int KDIM>
__device__ void stage1_body(const float* __restrict__ p, const float* __restrict__ mask,
                            const f16* __restrict__ hT_in, f16* __restrict__ tout,
                            f16* __restrict__ Wl) {
  const int tid = threadIdx.x;
  const int m = blockIdx.x;
  const int wave = tid >> 6, lane = tid & 63;
  const int row = lane & 15, kgrp = lane >> 4;
  const int grow = wave * 16 + row;

  const float pmx = p[m * 3 + 0], pmy = p[m * 3 + 1], pmz = p[m * 3 + 2];
  f32x4 acc[ITILES];
  #pragma unroll
  for (int it = 0; it < ITILES; ++it) acc[it] = f32x4{0.f, 0.f, 0.f, 0.f};

  #pragma unroll
  for (int half = 0; half < 2; ++half) {
    __syncthreads();
    int4* w4 = (int4*)Wl;
    int4 z4 = make_int4(0, 0, 0, 0);
    #pragma unroll
    for (int i = 0; i < 8; ++i) w4[tid + i * 256] = z4;     // zero 32KB
    __syncthreads();
    {
      const int n = half * 256 + tid;
      float x = (p[n * 3 + 0] - pmx) * INV_R;
      float y = (p[n * 3 + 1] - pmy) * INV_R;
      float z = (p[n * 3 + 2] - pmz) * INV_R;
      float r2 = x * x + y * y + z * z;
      float q = 1.0f - r2;
      float att = (q > 0.0f) ? q * q * q * mask[n] : 0.0f;
      bool c1 = (x == 0.0f) && (y == 0.0f);
      bool c2 = (fabsf(y) <= fabsf(x)) && !c1;
      float r = sqrtf(x * x + y * y + 1e-9f);
      float num = c2 ? y : x;
      float den = c2 ? x : y;
      float a = atan_poly(num / den);
      float s2 = copysignf(r, x), s3 = copysignf(r, y);
      const float C4PI = 1.2732395447351628f;
      float xs = c1 ? 0.0f : (c2 ? s2 : C4PI * s3 * a);
      float ys = c1 ? 0.0f : (c2 ? C4PI * s2 * a : s3);
      float zs = z;
      int iz0, iz1, iy0, iy1, ix0, ix1;
      float wz0, wz1, wy0, wy1, wx0, wx1;
      axis_w(zs, iz0, iz1, wz0, wz1);
      axis_w(ys, iy0, iy1, wy0, wy1);
      axis_w(xs, ix0, ix1, wx0, wx1);
      wz0 *= att; wz1 *= att;
      int gz[2] = {iz0 * 16, iz1 * 16};
      int gy[2] = {iy0 * 4, iy1 * 4};
      int gx[2] = {ix0, ix1};
      float wzv[2] = {wz0, wz1}, wyv[2] = {wy0, wy1}, wxv[2] = {wx0, wx1};
      #pragma unroll
      for (int za = 0; za < 2; ++za)
        #pragma unroll
        for (int ya = 0; ya < 2; ++ya)
          #pragma unroll
          for (int xa = 0; xa < 2; ++xa) {
            float w = wzv[za] * wyv[ya] * wxv[xa];
            if (w != 0.0f) {
              int g = gz[za] + gy[ya] + gx[xa];
              Wl[g * 256 + (tid ^ ((g & 7) << 3))] = (f16)w;
            }
          }
    }
    __syncthreads();
    #pragma unroll
    for (int k0 = 0; k0 < 8; ++k0) {
      const int n0l = k0 * 32 + kgrp * 8;
      f16x8 afrag = *(f16x8*)&Wl[grow * 256 + (n0l ^ ((grow & 7) << 3))];
      f16x8 bfr[ITILES];
      #pragma unroll
      for (int it = 0; it < ITILES; ++it)
        bfr[it] = *(const f16x8*)&hT_in[(it * 16 + row) * 512 + half * 256 + n0l];
      #pragma unroll
      for (int it = 0; it < ITILES; ++it)
        acc[it] = __builtin_amdgcn_mfma_f32_16x16x32_f16(afrag, bfr[it], acc[it], 0, 0, 0);
    }
  }
  const int g4 = wave * 16 + kgrp * 4;
  #pragma unroll
  for (int it = 0; it < ITILES; ++it) {
    const int icol = it * 16 + row;
    if (icol < CI) {
      union { f16 h[4]; iv2 i; } cv;
      #pragma unroll
      for (int r = 0; r < 4; ++r) cv.h[r] = (f16)acc[it][r];
      st_sys_b64(&tout[(size_t)m * KDIM + icol * 64 + g4], cv.i);   // [m][i*64+g]
    }
  }
}

// ============ stage 2: 128 tiles of 16m x 16o, 4-wave K-split, MFMA ============
template<int KDIM, bool RES, bool FINAL>
__device__ void stage2_body(const f16* __restrict__ t, const f16* __restrict__ Kf,
                            const float* __restrict__ bias, float* __restrict__ outG,
                            f16* __restrict__ hT_out, f16* __restrict__ tnext,
                            float* __restrict__ dout, float* __restrict__ red) {
  int b = blockIdx.x;
  if (b >= 128) return;
  int mtile = b >> 2, otile = b & 3;
  constexpr int KSTEPS = KDIM / 32;
  int tid = threadIdx.x;
  int kpart = tid >> 6, lane = tid & 63;
  int row = lane & 15, kgrp = lane >> 4;
  int mrow = mtile * 16 + row;
  int ocol = otile * 16 + row;
  f32x4 acc = {0.f, 0.f, 0.f, 0.f};
  for (int ks = kpart; ks < KSTEPS; ks += 4) {
    int k0 = ks * 32 + kgrp * 8;
    f16x8 afrag = *(const f16x8*)&t[(size_t)mrow * KDIM + k0];
    f16x8 bfrag = *(const f16x8*)&Kf[(size_t)ocol * KDIM + k0];
    acc = __builtin_amdgcn_mfma_f32_16x16x32_f16(afrag, bfrag, acc, 0, 0, 0);
  }
  if (kpart > 0) {
    #pragma unroll
    for (int r = 0; r < 4; ++r)
      red[(kpart - 1) * 256 + (kgrp * 4 + r) * 16 + row] = acc[r];
  }
  __syncthreads();
  if (kpart == 0) {
    #pragma unroll
    for (int kw = 0; kw < 3; ++kw)
      #pragma unroll
      for (int r = 0; r < 4; ++r)
        acc[r] += red[kw * 256 + (kgrp * 4 + r) * 16 + row];
    #pragma unroll
    for (int r = 0; r < 4; ++r) {
      int mm = mtile * 16 + kgrp * 4 + r;
      int oo = otile * 16 + row;
      if (FINAL) {
        if (oo < 6) dout[mm * 6 + oo] = acc[r] + bias[oo];
      } else {
        float val = acc[r] + bias[oo];
        if (RES) val += outG[mm * 64 + oo];                 // block-private RMW
        outG[mm * 64 + oo] = val;
        float h = fmaxf(val, 0.0f);
        unsigned hb = f16bits(h);
        st_sys_u16(&hT_out[oo * 512 + mm], hb);             // cross-block (sc01)
        st_sys_u16(&tnext[(size_t)mm * 4160 + 4096 + oo], hb);
      }
    }
  }
}

// ================= cooperative mega-kernel =================
__global__ __launch_bounds__(256, 2) void mega_kernel(
    const float* p, const float* v, const float* other, const float* mask,
    const float* kf, const float* Wf, const float* bf,
    const float* k1, const float* W1, const float* b1,
    const float* k2, const float* W2, const float* b2,
    const float* k3, const float* W3, const float* b3,
    const float* k4, const float* W4, const float* b4,
    float* dout, char* ws) {
  __shared__ int4 blob[2048];                // 32KB: stage1 W / stage2 red
  f16* Wl = (f16*)blob;
  float* red = (float*)blob;
  unsigned* bar = (unsigned*)(ws + F_BAR);

  f16* K0  = (f16*)(ws + F_K);
  float* B0 = (float*)(ws + F_B0);
  f16* hT0 = (f16*)(ws + F_HT);
  f16* hT1 = hT0 + 40960;
  f16* hT2 = hT0 + 81920;
  f16* hT3 = hT0 + 122880;
  f16* hT4 = hT0 + 163840;
  f16* t0 = (f16*)(ws + F_T0);
  f16* t1 = (f16*)(ws + F_T1);
  f16* t2 = (f16*)(ws + F_T2);
  f16* t3 = (f16*)(ws + F_T3);
  f16* t4 = (f16*)(ws + F_T4);
  float* outG = (float*)(ws + F_OG);

  prep_body(v, other, kf, Wf, bf, k1, W1, k2, W2, k3, W3, k4, W4, K0, B0, hT0, t0);
  gridbar(bar, 0);
  stage1_body<66, 5, 4320>(p, mask, hT0, t0, Wl);
  gridbar(bar, 1);
  stage2_body<4320, false, false>(t0, K0, B0, outG, hT1, t1, nullptr, red);
  gridbar(bar, 2);
  stage1_body<64, 4, 4160>(p, mask, hT1, t1, Wl);
  gridbar(bar, 3);
  stage2_body<4160, true, false>(t1, K0 + K1_OFF / 2, b1, outG, hT2, t2, nullptr, red);
  gridbar(bar, 4);
  stage1_body<64, 4, 4160>(p, mask, hT2, t2, Wl);
  gridbar(bar, 5);
  stage2_body<4160, true, false>(t2, K0 + K2_OFF / 2, b2, outG, hT3, t3, nullptr, red);
  gridbar(bar, 6);
  stage1_body<64, 4, 4160>(p, mask, hT3, t3, Wl);
  gridbar(bar, 7);
  stage2_body<4160, true, false>(t3, K0 + K3_OFF / 2, b3, outG, hT4, t4, nullptr, red);
  gridbar(bar, 8);
  stage1_body<64, 4, 4160>(p, mask, hT4, t4, Wl);
  gridbar(bar, 9);
  stage2_body<4160, false, true>(t4, K0 + K4_OFF / 2, b4, outG, nullptr, nullptr, dout, red);
}

// ================= fallback: same bodies, 11 plain launches =================
__global__ __launch_bounds__(256) void prep_g(
    const float* v, const float* other, const float* kf, const float* Wf, const float* bf,
    const float* k1, const float* W1, const float* k2, const float* W2,
    const float* k3, const float* W3, const float* k4, const float* W4,
    f16* K0, float* B0, f16* hT0, f16* t0) {
  prep_body(v, other, kf, Wf, bf, k1, W1, k2, W2, k3, W3, k4, W4, K0, B0, hT0, t0);
}
template<int CI, int ITILES, int KDIM>
__global__ __launch_bounds__(256) void stage1_g(const float* p, const float* mask,
                                                const f16* hT_in, f16* tout) {
  __shared__ int4 blob[2048];
  stage1_body<CI, ITILES, KDIM>(p, mask, hT_in, tout, (f16*)blob);
}
template<int KDIM, bool RES, bool FINAL>
__global__ __launch_bounds__(256) void stage2_g(const f16* t, const f16* Kf,
                                                const float* bias, float* outG,
                                                f16* hT_out, f16* tnext, float* dout) {
  __shared__ float red[3 * 256];
  stage2_body<KDIM, RES, FINAL>(t, Kf, bias, outG, hT_out, tnext, dout, red);
}

extern "C" void kernel_launch(void* const* d_in, const int* in_sizes, int n_in,
                              void* d_out, int out_size, void* d_ws, size_t ws_size,
                              hipStream_t stream) {
  const float* p     = (const float*)d_in[0];
  const float* v     = (const float*)d_in[1];
  const float* other = (const float*)d_in[2];
  const float* mask  = (const float*)d_in[3];
  const float* kf    = (const float*)d_in[4];
  const float* Wf    = (const float*)d_in[5];
  const float* bf    = (const float*)d_in[6];
  const float* k1    = (const float*)d_in[7];
  const float* W1    = (const float*)d_in[8];
  const float* b1    = (const float*)d_in[9];
  const float* k2    = (const float*)d_in[10];
  const float* W2    = (const float*)d_in[11];
  const float* b2    = (const float*)d_in[12];
  const float* k3    = (const float*)d_in[13];
  const float* W3    = (const float*)d_in[14];
  const float* b3    = (const float*)d_in[15];
  const float* k4    = (const float*)d_in[16];
  const float* W4    = (const float*)d_in[17];
  const float* b4    = (const float*)d_in[18];
  float* dout = (float*)d_out;
  char* ws = (char*)d_ws;
  (void)in_sizes; (void)n_in; (void)out_size;

  // ---- cooperative fused path (FULL layout) ----
  int maxb = 0;
  hipError_t e1 = hipOccupancyMaxActiveBlocksPerMultiprocessor(
      &maxb, (const void*)mega_kernel, 256, 0);
  if (e1 == hipSuccess && maxb >= 2 && ws_size >= NEED_FULL) {
    hipMemsetAsync(ws + F_BAR, 0, 2304, stream);
    void* args[] = {
      (void*)&p, (void*)&v, (void*)&other, (void*)&mask,
      (void*)&kf, (void*)&Wf, (void*)&bf,
      (void*)&k1, (void*)&W1, (void*)&b1,
      (void*)&k2, (void*)&W2, (void*)&b2,
      (void*)&k3, (void*)&W3, (void*)&b3,
      (void*)&k4, (void*)&W4, (void*)&b4,
      (void*)&dout, (void*)&ws
    };
    hipError_t e2 = hipLaunchCooperativeKernel((const void*)mega_kernel, dim3(NBLK),
                                               dim3(256), args, 0, stream);
    if (e2 == hipSuccess) return;
  }

  // ---- fallback (COMPACT layout): dispatch-boundary coherence, t/hT ping-pong ----
  f16* K0  = (f16*)(ws + C_K);
  float* B0 = (float*)(ws + C_B0);
  f16* hTA = (f16*)(ws + C_HTA);
  f16* hTB = (f16*)(ws + C_HTB);
  f16* tA  = (f16*)(ws + C_TA);
  f16* tB  = (f16*)(ws + C_TB);
  float* outG = (float*)(ws + C_OG);

  prep_g<<<NBLK, 256, 0, stream>>>(v, other, kf, Wf, bf, k1, W1, k2, W2, k3, W3, k4, W4,
                                   K0, B0, hTA, tA);
  stage1_g<66, 5, 4320><<<NBLK, 256, 0, stream>>>(p, mask, hTA, tA);
  stage2_g<4320, false, false><<<128, 256, 0, stream>>>(tA, K0, B0, outG, hTB, tB, nullptr);
  stage1_g<64, 4, 4160><<<NBLK, 256, 0, stream>>>(p, mask, hTB, tB);
  stage2_g<4160, true, false><<<128, 256, 0, stream>>>(tB, K0 + K1_OFF / 2, b1, outG, hTA, tA, nullptr);
  stage1_g<64, 4, 4160><<<NBLK, 256, 0, stream>>>(p, mask, hTA, tA);
  stage2_g<4160, true, false><<<128, 256, 0, stream>>>(tA, K0 + K2_OFF / 2, b2, outG, hTB, tB, nullptr);
  stage1_g<64, 4, 4160><<<NBLK, 256, 0, stream>>>(p, mask, hTB, tB);
  stage2_g<4160, true, false><<<128, 256, 0, stream>>>(tB, K0 + K3_OFF / 2, b3, outG, hTA, tA, nullptr);
  stage1_g<64, 4, 4160><<<NBLK, 256, 0, stream>>>(p, mask, hTA, tA);
  stage2_g<4160, false, true><<<128, 256, 0, stream>>>(tA, K0 + K4_OFF / 2, b4, outG, nullptr, nullptr, dout);
}